// Round 18
// baseline (3578.901 us; speedup 1.0000x reference)
//
#include <hip/hip_runtime.h>

// Net_46076409152296: spiking net fwd (RLeaky+Leaky). B=1024,T=32,D=2312,H=512,O=10.
// v18: K1 = v15 structure with X tile stored f32 in LDS (Ws stays f64).
//  - LDS/block 41KB -> 30.7KB (crosses the 32KB boundary: 2 blocks/CU if the
//    effective LDS pool is 64KB — occupancy counter will disambiguate)
//  - A-side LDS reads halve (2x b128 f32 + 8 in-reg cvt per kk; cvt is exact,
//    math bit-identical to v15/v17: same f64 fma order)
// K0 + sparse K2 + launcher verbatim from v17 (measured: K2 ~0.55ms).

constexpr int Bq = 1024, Tq = 32, Dq = 2312, Hq = 512, Oq = 10;

// ---------------- K0: WrT[k][j] = (double)Wr[j][k]  (coalesced transpose)
__global__ __launch_bounds__(256) void snn_wrt(
    const float* __restrict__ Wr, double* __restrict__ WrT) {
  __shared__ float t[32][33];
  const int bx = blockIdx.x;          // k-tile
  const int by = blockIdx.y;          // j-tile
  const int lx = threadIdx.x & 31, ly = threadIdx.x >> 5;  // 32 x 8
#pragma unroll
  for (int i = 0; i < 4; ++i)
    t[ly + 8 * i][lx] = Wr[(size_t)(by * 32 + ly + 8 * i) * Hq + bx * 32 + lx];
  __syncthreads();
#pragma unroll
  for (int i = 0; i < 4; ++i)
    WrT[(size_t)(bx * 32 + ly + 8 * i) * Hq + by * 32 + lx] =
        (double)t[lx][ly + 8 * i];
}

// ---------------- K1: C[m][n] = f64dot(x[m,:], W1[n,:]) + b1[n]
__global__ __launch_bounds__(256) void snn_fc1_gemm(
    const float* __restrict__ x, const float* __restrict__ W1,
    const float* __restrict__ b1, float* __restrict__ cur1) {
  __shared__ float  Xs[2][8][160];   // 10.25 KB (f32; chunk c at [kk][c*10..+7])
  __shared__ double Ws[2][8][160];   // 20.5 KB  (f64)

  const int tid = threadIdx.x;
  const int tx = tid & 15;
  const int ty = tid >> 4;
  const size_t m0 = (size_t)blockIdx.y * 128;
  const int n0 = blockIdx.x * 128;
  const int srow = tid >> 1;
  const int sko = (tid & 1) * 4;
  const int schunk = (srow >> 3) * 10 + (srow & 7);
  const float* __restrict__ ax = x + (m0 + srow) * Dq + sko;
  const float* __restrict__ bx = W1 + (size_t)(n0 + srow) * Dq + sko;

  double acc[8][8];
#pragma unroll
  for (int i = 0; i < 8; ++i)
#pragma unroll
    for (int j = 0; j < 8; ++j) acc[i][j] = 0.0;

  float4 av = *(const float4*)(ax);
  float4 bv = *(const float4*)(bx);
  Xs[0][sko + 0][schunk] = av.x;
  Xs[0][sko + 1][schunk] = av.y;
  Xs[0][sko + 2][schunk] = av.z;
  Xs[0][sko + 3][schunk] = av.w;
  Ws[0][sko + 0][schunk] = (double)bv.x;
  Ws[0][sko + 1][schunk] = (double)bv.y;
  Ws[0][sko + 2][schunk] = (double)bv.z;
  Ws[0][sko + 3][schunk] = (double)bv.w;
  __syncthreads();

  for (int s = 0; s < 289; ++s) {        // D = 289 * 8
    const int buf = s & 1;
    if (s + 1 < 289) {
      av = *(const float4*)(ax + (s + 1) * 8);
      bv = *(const float4*)(bx + (s + 1) * 8);
    }
#pragma unroll
    for (int kk = 0; kk < 8; ++kk) {
      float af[8];
      *(float4*)&af[0] = *(const float4*)&Xs[buf][kk][ty * 10 + 0];
      *(float4*)&af[4] = *(const float4*)&Xs[buf][kk][ty * 10 + 4];
      double a[8], b[8];
#pragma unroll
      for (int i = 0; i < 8; ++i) a[i] = (double)af[i];  // exact
      *(double2*)&b[0] = *(const double2*)&Ws[buf][kk][tx * 10 + 0];
      *(double2*)&b[2] = *(const double2*)&Ws[buf][kk][tx * 10 + 2];
      *(double2*)&b[4] = *(const double2*)&Ws[buf][kk][tx * 10 + 4];
      *(double2*)&b[6] = *(const double2*)&Ws[buf][kk][tx * 10 + 6];
#pragma unroll
      for (int i = 0; i < 8; ++i)
#pragma unroll
        for (int j = 0; j < 8; ++j) acc[i][j] = fma(a[i], b[j], acc[i][j]);
    }
    if (s + 1 < 289) {
      const int nb = buf ^ 1;
      Xs[nb][sko + 0][schunk] = av.x;
      Xs[nb][sko + 1][schunk] = av.y;
      Xs[nb][sko + 2][schunk] = av.z;
      Xs[nb][sko + 3][schunk] = av.w;
      Ws[nb][sko + 0][schunk] = (double)bv.x;
      Ws[nb][sko + 1][schunk] = (double)bv.y;
      Ws[nb][sko + 2][schunk] = (double)bv.z;
      Ws[nb][sko + 3][schunk] = (double)bv.w;
      __syncthreads();
    }
  }

  float bl[8];
  *(float4*)&bl[0] = *(const float4*)(b1 + n0 + tx * 8);
  *(float4*)&bl[4] = *(const float4*)(b1 + n0 + tx * 8 + 4);
#pragma unroll
  for (int i = 0; i < 8; ++i) {
    float* crow = cur1 + (m0 + ty * 8 + i) * Hq + n0 + tx * 8;
    float4 v0, v1;
    v0.x = __fadd_rn((float)acc[i][0], bl[0]);
    v0.y = __fadd_rn((float)acc[i][1], bl[1]);
    v0.z = __fadd_rn((float)acc[i][2], bl[2]);
    v0.w = __fadd_rn((float)acc[i][3], bl[3]);
    v1.x = __fadd_rn((float)acc[i][4], bl[4]);
    v1.y = __fadd_rn((float)acc[i][5], bl[5]);
    v1.z = __fadd_rn((float)acc[i][6], bl[6]);
    v1.w = __fadd_rn((float)acc[i][7], bl[7]);
    *(float4*)(crow) = v0;
    *(float4*)(crow + 4) = v1;
  }
}

// ---------------- K2 helpers: pipelined sparse gather
__device__ __forceinline__ void gather8(const unsigned short* __restrict__ row,
                                        int base, int j,
                                        const double* __restrict__ WrT,
                                        double* g) {
  const uint4 pk = *(const uint4*)&row[base];
  const int k0 = pk.x & 0xffff, k1 = pk.x >> 16;
  const int k2 = pk.y & 0xffff, k3 = pk.y >> 16;
  const int k4 = pk.z & 0xffff, k5 = pk.z >> 16;
  const int k6 = pk.w & 0xffff, k7 = pk.w >> 16;
  g[0] = WrT[(size_t)k0 * Hq + j];
  g[1] = WrT[(size_t)k1 * Hq + j];
  g[2] = WrT[(size_t)k2 * Hq + j];
  g[3] = WrT[(size_t)k3 * Hq + j];
  g[4] = WrT[(size_t)k4 * Hq + j];
  g[5] = WrT[(size_t)k5 * Hq + j];
  g[6] = WrT[(size_t)k6 * Hq + j];
  g[7] = WrT[(size_t)k7 * Hq + j];
}
__device__ __forceinline__ void acc8(const double* g, int rem, double& rA,
                                     double& rB, double& rC, double& rD) {
  if (rem >= 8) {
    rA += g[0]; rB += g[1]; rC += g[2]; rD += g[3];
    rA += g[4]; rB += g[5]; rC += g[6]; rD += g[7];
  } else {
    if (rem > 0) rA += g[0];
    if (rem > 1) rB += g[1];
    if (rem > 2) rC += g[2];
    if (rem > 3) rD += g[3];
    if (rem > 4) rA += g[4];
    if (rem > 5) rB += g[5];
    if (rem > 6) rC += g[6];
  }
}

// ---------------- K2: sparse-spike recurrent scan (v16 verbatim)
__global__ __launch_bounds__(512) void snn_scan(
    const float* __restrict__ cur1, const double* __restrict__ WrT,
    const float* __restrict__ br, const float* __restrict__ W2,
    const float* __restrict__ b2, float* __restrict__ out, int b_off) {
  __shared__ float spkF[4][512];                // 8 KB (fc2)
  __shared__ unsigned short idxL[4][512];       // 4 KB (active k lists)
  __shared__ unsigned long long masksL[4][8];   // 256 B
  __shared__ int cnts[4];

  const int j = threadIdx.x;
  const int wv = j >> 6;
  const int lane = j & 63;
  const int lb = blockIdx.x * 4;
  const int gb = b_off + lb;

  float m1[4] = {0.f, 0.f, 0.f, 0.f};
  float m2 = 0.f;
#pragma unroll
  for (int r = 0; r < 4; ++r) { spkF[r][j] = 0.f; idxL[r][j] = 0; }
  if (j < 4) cnts[j] = 0;
  __syncthreads();

  const float brr = br[j];

  const int g = j >> 3, l = j & 7;
  const int r2g = g / 10, o2 = g - r2g * 10;
  const bool doB = (j < 320);
  const float b2v = doB ? b2[o2] : 0.f;
  const float* __restrict__ w2p = doB ? (W2 + (size_t)o2 * Hq) : W2;

  for (int t = 0; t < Tq; ++t) {
    float c1[4];
#pragma unroll
    for (int r = 0; r < 4; ++r)
      c1[r] = cur1[((size_t)(lb + r) * Tq + t) * Hq + j];

    // ---- sparse rec: rec[r] = sum over active k of WrT[k][j] ----
    double rec[4];
#pragma unroll
    for (int r = 0; r < 4; ++r) {
      const int cnt = cnts[r];
      double rA = 0.0, rB = 0.0, rC = 0.0, rD = 0.0;
      double g0[8], g1[8];
      if (cnt > 0) gather8(&idxL[r][0], 0, j, WrT, g0);
      for (int i0 = 0; i0 < cnt; i0 += 16) {
        if (i0 + 8 < cnt) gather8(&idxL[r][0], i0 + 8, j, WrT, g1);
        acc8(g0, cnt - i0, rA, rB, rC, rD);
        if (i0 + 16 < cnt) gather8(&idxL[r][0], i0 + 16, j, WrT, g0);
        if (i0 + 8 < cnt) acc8(g1, cnt - (i0 + 8), rA, rB, rC, rD);
      }
      rec[r] = (rA + rB) + (rC + rD);
    }
    __syncthreads();  // rec reads done; idxL/masksL/spkF free to overwrite

    // ---- state update + ballots ----
    unsigned long long bm[4];
    int bits = 0;
#pragma unroll
    for (int r = 0; r < 4; ++r) {
      const float rst = (m1[r] - 1.0f > 0.0f) ? 1.0f : 0.0f;
      const float mn = __fsub_rn(
          __fadd_rn(__fadd_rn(__fmul_rn(0.99f, m1[r]), c1[r]),
                    __fadd_rn((float)rec[r], brr)),
          rst);
      m1[r] = mn;
      const bool bit = (mn - 1.0f > 0.0f);
      spkF[r][j] = bit ? 1.0f : 0.0f;
      if (bit) bits |= (1 << r);
      bm[r] = __ballot(bit);
      if (lane == 0) masksL[r][wv] = bm[r];
    }
    __syncthreads();  // masksL + spkF visible

    // ---- compaction: positions + counts ----
#pragma unroll
    for (int r = 0; r < 4; ++r) {
      int base = 0;
#pragma unroll
      for (int w = 0; w < 8; ++w)
        if (w < wv) base += __popcll(masksL[r][w]);
      if (bits & (1 << r)) {
        const int pos = base + __popcll(bm[r] & ((1ull << lane) - 1ull));
        idxL[r][pos] = (unsigned short)j;
      }
    }
    if (j < 4) {
      int c = 0;
#pragma unroll
      for (int w = 0; w < 8; ++w) c += __popcll(masksL[j][w]);
      cnts[j] = c;
    }
    // ---- fc2 + mem2 + outputs (dense, 8 lanes per dot) ----
    if (doB) {
      double p = 0.0;
#pragma unroll
      for (int s8 = 0; s8 < 64; ++s8) {
        const int k = l + (s8 << 3);
        p = fma((double)spkF[r2g][k], (double)w2p[k], p);
      }
      p += __shfl_down(p, 4, 8);
      p += __shfl_down(p, 2, 8);
      p += __shfl_down(p, 1, 8);
      if (l == 0) {
        const float cur2 = __fadd_rn((float)p, b2v);
        const float rst2 = (m2 - 1.0f > 0.0f) ? 1.0f : 0.0f;
        const float mn2 =
            __fsub_rn(__fadd_rn(__fmul_rn(0.99f, m2), cur2), rst2);
        m2 = mn2;
        const size_t oidx = ((size_t)t * Bq + (gb + r2g)) * Oq + o2;
        out[oidx] = (mn2 - 1.0f > 0.0f) ? 1.0f : 0.0f;  // spk2
        out[(size_t)Tq * Bq * Oq + oidx] = mn2;         // mem2
      }
    }
    __syncthreads();  // idxL/cnts ready for next step's rec
  }
}

extern "C" void kernel_launch(void* const* d_in, const int* in_sizes, int n_in,
                              void* d_out, int out_size, void* d_ws, size_t ws_size,
                              hipStream_t stream) {
  const float* x  = (const float*)d_in[0];
  const float* W1 = (const float*)d_in[1];
  const float* b1 = (const float*)d_in[2];
  const float* Wr = (const float*)d_in[3];
  const float* br = (const float*)d_in[4];
  const float* W2 = (const float*)d_in[5];
  const float* b2 = (const float*)d_in[6];
  float* out = (float*)d_out;  // FP32
  (void)in_sizes; (void)n_in; (void)out_size;

  double* WrT = (double*)d_ws;                       // 2 MB
  float* cur1 = (float*)d_ws + 2 * Hq * Hq;          // after WrT (in floats)
  const size_t avail = ws_size - (size_t)Hq * Hq * sizeof(double);

  snn_wrt<<<dim3(16, 16), 256, 0, stream>>>(Wr, WrT);

  int nb = Bq;
  while (nb > 4 && (size_t)nb * Tq * Hq * sizeof(float) > avail) nb >>= 1;

  for (int b_off = 0; b_off < Bq; b_off += nb) {
    snn_fc1_gemm<<<dim3(Hq / 128, nb * Tq / 128), 256, 0, stream>>>(
        x + (size_t)b_off * Tq * Dq, W1, b1, cur1);
    snn_scan<<<nb / 4, 512, 0, stream>>>(cur1, WrT, br, W2, b2, out, b_off);
  }
}

// Round 19
// 3009.353 us; speedup vs baseline: 1.1893x; 1.1893x over previous
//
#include <hip/hip_runtime.h>

// Net_46076409152296: spiking net fwd (RLeaky+Leaky). B=1024,T=32,D=2312,H=512,O=10.
// v19: K1 = v17 all-f64-LDS inner loop + __launch_bounds__(256,1) (full 256-VGPR
//      budget at the 1-wave/SIMD occupancy we're pinned to anyway) + explicit
//      fragment double-buffering (kk unroll-by-2, static indices) to overlap
//      LDS-read latency with f64 fma issue. Math bit-identical to v15/v17.
//      K2 = sparse scan with WrT stored f32 (L2 traffic halved; cvt exact).
// Occupancy map measured: VGPR {64:46%, 128:24%, 212:12%} -> pool ~256/SIMD;
// 8x8 f64 acc forces 1 wave/SIMD, so pipeline within the wave instead.

constexpr int Bq = 1024, Tq = 32, Dq = 2312, Hq = 512, Oq = 10;

// ---------------- K0: WrTf[k][j] = Wr[j][k]  (f32 coalesced transpose)
__global__ __launch_bounds__(256) void snn_wrt(
    const float* __restrict__ Wr, float* __restrict__ WrTf) {
  __shared__ float t[32][33];
  const int bx = blockIdx.x;          // k-tile
  const int by = blockIdx.y;          // j-tile
  const int lx = threadIdx.x & 31, ly = threadIdx.x >> 5;  // 32 x 8
#pragma unroll
  for (int i = 0; i < 4; ++i)
    t[ly + 8 * i][lx] = Wr[(size_t)(by * 32 + ly + 8 * i) * Hq + bx * 32 + lx];
  __syncthreads();
#pragma unroll
  for (int i = 0; i < 4; ++i)
    WrTf[(size_t)(bx * 32 + ly + 8 * i) * Hq + by * 32 + lx] = t[lx][ly + 8 * i];
}

// ---------------- K1: C[m][n] = f64dot(x[m,:], W1[n,:]) + b1[n]
__global__ __launch_bounds__(256, 1) void snn_fc1_gemm(
    const float* __restrict__ x, const float* __restrict__ W1,
    const float* __restrict__ b1, float* __restrict__ cur1) {
  __shared__ double Xs[2][8][160];   // chunk c at [kk][c*10..c*10+7]
  __shared__ double Ws[2][8][160];

  const int tid = threadIdx.x;
  const int tx = tid & 15;
  const int ty = tid >> 4;
  const size_t m0 = (size_t)blockIdx.y * 128;
  const int n0 = blockIdx.x * 128;
  const int srow = tid >> 1;
  const int sko = (tid & 1) * 4;
  const int schunk = (srow >> 3) * 10 + (srow & 7);
  const float* __restrict__ ax = x + (m0 + srow) * Dq + sko;
  const float* __restrict__ bx = W1 + (size_t)(n0 + srow) * Dq + sko;

  double acc[8][8];
#pragma unroll
  for (int i = 0; i < 8; ++i)
#pragma unroll
    for (int j = 0; j < 8; ++j) acc[i][j] = 0.0;

  float4 av = *(const float4*)(ax);
  float4 bv = *(const float4*)(bx);
  Xs[0][sko + 0][schunk] = (double)av.x;
  Xs[0][sko + 1][schunk] = (double)av.y;
  Xs[0][sko + 2][schunk] = (double)av.z;
  Xs[0][sko + 3][schunk] = (double)av.w;
  Ws[0][sko + 0][schunk] = (double)bv.x;
  Ws[0][sko + 1][schunk] = (double)bv.y;
  Ws[0][sko + 2][schunk] = (double)bv.z;
  Ws[0][sko + 3][schunk] = (double)bv.w;
  __syncthreads();

  // fragment load/fma helpers (all static indices)
#define FRAG_LOAD(A, Bv, BUF, KK)                                        \
  do {                                                                   \
    *(double2*)&(A)[0] = *(const double2*)&Xs[BUF][KK][ty * 10 + 0];     \
    *(double2*)&(A)[2] = *(const double2*)&Xs[BUF][KK][ty * 10 + 2];     \
    *(double2*)&(A)[4] = *(const double2*)&Xs[BUF][KK][ty * 10 + 4];     \
    *(double2*)&(A)[6] = *(const double2*)&Xs[BUF][KK][ty * 10 + 6];     \
    *(double2*)&(Bv)[0] = *(const double2*)&Ws[BUF][KK][tx * 10 + 0];    \
    *(double2*)&(Bv)[2] = *(const double2*)&Ws[BUF][KK][tx * 10 + 2];    \
    *(double2*)&(Bv)[4] = *(const double2*)&Ws[BUF][KK][tx * 10 + 4];    \
    *(double2*)&(Bv)[6] = *(const double2*)&Ws[BUF][KK][tx * 10 + 6];    \
  } while (0)
#define FRAG_FMA(A, Bv)                                                  \
  do {                                                                   \
    _Pragma("unroll") for (int i = 0; i < 8; ++i)                        \
        _Pragma("unroll") for (int j = 0; j < 8; ++j)                    \
            acc[i][j] = fma((A)[i], (Bv)[j], acc[i][j]);                 \
  } while (0)

  for (int s = 0; s < 289; ++s) {        // D = 289 * 8
    const int buf = s & 1;
    if (s + 1 < 289) {                   // early-issue next slab's global loads
      av = *(const float4*)(ax + (s + 1) * 8);
      bv = *(const float4*)(bx + (s + 1) * 8);
    }
    {
      double aA[8], bA[8], aB[8], bB[8];
      FRAG_LOAD(aA, bA, buf, 0);
      FRAG_LOAD(aB, bB, buf, 1);
      FRAG_FMA(aA, bA);
      FRAG_LOAD(aA, bA, buf, 2);
      FRAG_FMA(aB, bB);
      FRAG_LOAD(aB, bB, buf, 3);
      FRAG_FMA(aA, bA);
      FRAG_LOAD(aA, bA, buf, 4);
      FRAG_FMA(aB, bB);
      FRAG_LOAD(aB, bB, buf, 5);
      FRAG_FMA(aA, bA);
      FRAG_LOAD(aA, bA, buf, 6);
      FRAG_FMA(aB, bB);
      FRAG_LOAD(aB, bB, buf, 7);
      FRAG_FMA(aA, bA);
      FRAG_FMA(aB, bB);
    }
    if (s + 1 < 289) {
      const int nb = buf ^ 1;
      Xs[nb][sko + 0][schunk] = (double)av.x;
      Xs[nb][sko + 1][schunk] = (double)av.y;
      Xs[nb][sko + 2][schunk] = (double)av.z;
      Xs[nb][sko + 3][schunk] = (double)av.w;
      Ws[nb][sko + 0][schunk] = (double)bv.x;
      Ws[nb][sko + 1][schunk] = (double)bv.y;
      Ws[nb][sko + 2][schunk] = (double)bv.z;
      Ws[nb][sko + 3][schunk] = (double)bv.w;
      __syncthreads();
    }
  }
#undef FRAG_LOAD
#undef FRAG_FMA

  float bl[8];
  *(float4*)&bl[0] = *(const float4*)(b1 + n0 + tx * 8);
  *(float4*)&bl[4] = *(const float4*)(b1 + n0 + tx * 8 + 4);
#pragma unroll
  for (int i = 0; i < 8; ++i) {
    float* crow = cur1 + (m0 + ty * 8 + i) * Hq + n0 + tx * 8;
    float4 v0, v1;
    v0.x = __fadd_rn((float)acc[i][0], bl[0]);
    v0.y = __fadd_rn((float)acc[i][1], bl[1]);
    v0.z = __fadd_rn((float)acc[i][2], bl[2]);
    v0.w = __fadd_rn((float)acc[i][3], bl[3]);
    v1.x = __fadd_rn((float)acc[i][4], bl[4]);
    v1.y = __fadd_rn((float)acc[i][5], bl[5]);
    v1.z = __fadd_rn((float)acc[i][6], bl[6]);
    v1.w = __fadd_rn((float)acc[i][7], bl[7]);
    *(float4*)(crow) = v0;
    *(float4*)(crow + 4) = v1;
  }
}

// ---------------- K2 helpers: pipelined sparse gather (WrT in f32; cvt exact)
__device__ __forceinline__ void gather8(const unsigned short* __restrict__ row,
                                        int base, int j,
                                        const float* __restrict__ WrTf,
                                        double* g) {
  const uint4 pk = *(const uint4*)&row[base];
  const int k0 = pk.x & 0xffff, k1 = pk.x >> 16;
  const int k2 = pk.y & 0xffff, k3 = pk.y >> 16;
  const int k4 = pk.z & 0xffff, k5 = pk.z >> 16;
  const int k6 = pk.w & 0xffff, k7 = pk.w >> 16;
  g[0] = (double)WrTf[(size_t)k0 * Hq + j];
  g[1] = (double)WrTf[(size_t)k1 * Hq + j];
  g[2] = (double)WrTf[(size_t)k2 * Hq + j];
  g[3] = (double)WrTf[(size_t)k3 * Hq + j];
  g[4] = (double)WrTf[(size_t)k4 * Hq + j];
  g[5] = (double)WrTf[(size_t)k5 * Hq + j];
  g[6] = (double)WrTf[(size_t)k6 * Hq + j];
  g[7] = (double)WrTf[(size_t)k7 * Hq + j];
}
__device__ __forceinline__ void acc8(const double* g, int rem, double& rA,
                                     double& rB, double& rC, double& rD) {
  if (rem >= 8) {
    rA += g[0]; rB += g[1]; rC += g[2]; rD += g[3];
    rA += g[4]; rB += g[5]; rC += g[6]; rD += g[7];
  } else {
    if (rem > 0) rA += g[0];
    if (rem > 1) rB += g[1];
    if (rem > 2) rC += g[2];
    if (rem > 3) rD += g[3];
    if (rem > 4) rA += g[4];
    if (rem > 5) rB += g[5];
    if (rem > 6) rC += g[6];
  }
}

// ---------------- K2: sparse-spike recurrent scan
__global__ __launch_bounds__(512) void snn_scan(
    const float* __restrict__ cur1, const float* __restrict__ WrTf,
    const float* __restrict__ br, const float* __restrict__ W2,
    const float* __restrict__ b2, float* __restrict__ out, int b_off) {
  __shared__ float spkF[4][512];                // 8 KB (fc2)
  __shared__ unsigned short idxL[4][512];       // 4 KB (active k lists)
  __shared__ unsigned long long masksL[4][8];   // 256 B
  __shared__ int cnts[4];

  const int j = threadIdx.x;
  const int wv = j >> 6;
  const int lane = j & 63;
  const int lb = blockIdx.x * 4;
  const int gb = b_off + lb;

  float m1[4] = {0.f, 0.f, 0.f, 0.f};
  float m2 = 0.f;
#pragma unroll
  for (int r = 0; r < 4; ++r) { spkF[r][j] = 0.f; idxL[r][j] = 0; }
  if (j < 4) cnts[j] = 0;
  __syncthreads();

  const float brr = br[j];

  const int g = j >> 3, l = j & 7;
  const int r2g = g / 10, o2 = g - r2g * 10;
  const bool doB = (j < 320);
  const float b2v = doB ? b2[o2] : 0.f;
  const float* __restrict__ w2p = doB ? (W2 + (size_t)o2 * Hq) : W2;

  for (int t = 0; t < Tq; ++t) {
    float c1[4];
#pragma unroll
    for (int r = 0; r < 4; ++r)
      c1[r] = cur1[((size_t)(lb + r) * Tq + t) * Hq + j];

    // ---- sparse rec: rec[r] = sum over active k of WrT[k][j] ----
    double rec[4];
#pragma unroll
    for (int r = 0; r < 4; ++r) {
      const int cnt = cnts[r];
      double rA = 0.0, rB = 0.0, rC = 0.0, rD = 0.0;
      double g0[8], g1[8];
      if (cnt > 0) gather8(&idxL[r][0], 0, j, WrTf, g0);
      for (int i0 = 0; i0 < cnt; i0 += 16) {
        if (i0 + 8 < cnt) gather8(&idxL[r][0], i0 + 8, j, WrTf, g1);
        acc8(g0, cnt - i0, rA, rB, rC, rD);
        if (i0 + 16 < cnt) gather8(&idxL[r][0], i0 + 16, j, WrTf, g0);
        if (i0 + 8 < cnt) acc8(g1, cnt - (i0 + 8), rA, rB, rC, rD);
      }
      rec[r] = (rA + rB) + (rC + rD);
    }
    __syncthreads();  // rec reads done; idxL/masksL/spkF free to overwrite

    // ---- state update + ballots ----
    unsigned long long bm[4];
    int bits = 0;
#pragma unroll
    for (int r = 0; r < 4; ++r) {
      const float rst = (m1[r] - 1.0f > 0.0f) ? 1.0f : 0.0f;
      const float mn = __fsub_rn(
          __fadd_rn(__fadd_rn(__fmul_rn(0.99f, m1[r]), c1[r]),
                    __fadd_rn((float)rec[r], brr)),
          rst);
      m1[r] = mn;
      const bool bit = (mn - 1.0f > 0.0f);
      spkF[r][j] = bit ? 1.0f : 0.0f;
      if (bit) bits |= (1 << r);
      bm[r] = __ballot(bit);
      if (lane == 0) masksL[r][wv] = bm[r];
    }
    __syncthreads();  // masksL + spkF visible

    // ---- compaction: positions + counts ----
#pragma unroll
    for (int r = 0; r < 4; ++r) {
      int base = 0;
#pragma unroll
      for (int w = 0; w < 8; ++w)
        if (w < wv) base += __popcll(masksL[r][w]);
      if (bits & (1 << r)) {
        const int pos = base + __popcll(bm[r] & ((1ull << lane) - 1ull));
        idxL[r][pos] = (unsigned short)j;
      }
    }
    if (j < 4) {
      int c = 0;
#pragma unroll
      for (int w = 0; w < 8; ++w) c += __popcll(masksL[j][w]);
      cnts[j] = c;
    }
    // ---- fc2 + mem2 + outputs (dense, 8 lanes per dot) ----
    if (doB) {
      double p = 0.0;
#pragma unroll
      for (int s8 = 0; s8 < 64; ++s8) {
        const int k = l + (s8 << 3);
        p = fma((double)spkF[r2g][k], (double)w2p[k], p);
      }
      p += __shfl_down(p, 4, 8);
      p += __shfl_down(p, 2, 8);
      p += __shfl_down(p, 1, 8);
      if (l == 0) {
        const float cur2 = __fadd_rn((float)p, b2v);
        const float rst2 = (m2 - 1.0f > 0.0f) ? 1.0f : 0.0f;
        const float mn2 =
            __fsub_rn(__fadd_rn(__fmul_rn(0.99f, m2), cur2), rst2);
        m2 = mn2;
        const size_t oidx = ((size_t)t * Bq + (gb + r2g)) * Oq + o2;
        out[oidx] = (mn2 - 1.0f > 0.0f) ? 1.0f : 0.0f;  // spk2
        out[(size_t)Tq * Bq * Oq + oidx] = mn2;         // mem2
      }
    }
    __syncthreads();  // idxL/cnts ready for next step's rec
  }
}

extern "C" void kernel_launch(void* const* d_in, const int* in_sizes, int n_in,
                              void* d_out, int out_size, void* d_ws, size_t ws_size,
                              hipStream_t stream) {
  const float* x  = (const float*)d_in[0];
  const float* W1 = (const float*)d_in[1];
  const float* b1 = (const float*)d_in[2];
  const float* Wr = (const float*)d_in[3];
  const float* br = (const float*)d_in[4];
  const float* W2 = (const float*)d_in[5];
  const float* b2 = (const float*)d_in[6];
  float* out = (float*)d_out;  // FP32
  (void)in_sizes; (void)n_in; (void)out_size;

  float* WrTf = (float*)d_ws;                        // 1 MB
  float* cur1 = (float*)d_ws + Hq * Hq;              // after WrTf
  const size_t avail = ws_size - (size_t)Hq * Hq * sizeof(float);

  snn_wrt<<<dim3(16, 16), 256, 0, stream>>>(Wr, WrTf);

  int nb = Bq;
  while (nb > 4 && (size_t)nb * Tq * Hq * sizeof(float) > avail) nb >>= 1;

  for (int b_off = 0; b_off < Bq; b_off += nb) {
    snn_fc1_gemm<<<dim3(Hq / 128, nb * Tq / 128), 256, 0, stream>>>(
        x + (size_t)b_off * Tq * Dq, W1, b1, cur1);
    snn_scan<<<nb / 4, 512, 0, stream>>>(cur1, WrTf, br, W2, b2, out, b_off);
  }
}

// Round 20
// 2369.140 us; speedup vs baseline: 1.5106x; 1.2702x over previous
//
#include <hip/hip_runtime.h>

// Net_46076409152296: spiking net fwd (RLeaky+Leaky). B=1024,T=32,D=2312,H=512,O=10.
// v20: K1 BK 8->12 (slabs 289->193, barrier/startup overhead x0.67; 61.4KB LDS,
//      under the 64KB static cap). Per-dot fma order unchanged (ascending k) ->
//      bit-identical. K0 + sparse-f32-WrT K2 + launcher verbatim v19.
// Occupancy is VGPR-pinned to 1 wave/SIMD (measured map: 64->46%,128->24%,212->12%)
// so the lever is per-slab overhead, not TLP.

constexpr int Bq = 1024, Tq = 32, Dq = 2312, Hq = 512, Oq = 10;

// ---------------- K0: WrTf[k][j] = Wr[j][k]  (f32 coalesced transpose)
__global__ __launch_bounds__(256) void snn_wrt(
    const float* __restrict__ Wr, float* __restrict__ WrTf) {
  __shared__ float t[32][33];
  const int bx = blockIdx.x;
  const int by = blockIdx.y;
  const int lx = threadIdx.x & 31, ly = threadIdx.x >> 5;
#pragma unroll
  for (int i = 0; i < 4; ++i)
    t[ly + 8 * i][lx] = Wr[(size_t)(by * 32 + ly + 8 * i) * Hq + bx * 32 + lx];
  __syncthreads();
#pragma unroll
  for (int i = 0; i < 4; ++i)
    WrTf[(size_t)(bx * 32 + ly + 8 * i) * Hq + by * 32 + lx] = t[lx][ly + 8 * i];
}

// ---------------- K1: C[m][n] = f64dot(x[m,:], W1[n,:]) + b1[n]
// 128x128 tile, 256 thr, 8x8 micro, BK=12 (+8 tail), f64 LDS chunk-padded.
__global__ __launch_bounds__(256) void snn_fc1_gemm(
    const float* __restrict__ x, const float* __restrict__ W1,
    const float* __restrict__ b1, float* __restrict__ cur1) {
  __shared__ double Xs[2][12][160];   // 30.72 KB (chunk c at [kk][c*10..+7])
  __shared__ double Ws[2][12][160];   // 30.72 KB

  const int tid = threadIdx.x;
  const int tx = tid & 15;
  const int ty = tid >> 4;
  const size_t m0 = (size_t)blockIdx.y * 128;
  const int n0 = blockIdx.x * 128;
  const int srow = tid >> 1;              // 0..127
  const int kc6 = (tid & 1) * 6;          // 0 or 6  (main slabs, width 12)
  const int kc4 = (tid & 1) * 4;          // 0 or 4  (tail slab, width 8)
  const int schunk = (srow >> 3) * 10 + (srow & 7);
  const float* __restrict__ ax = x + (m0 + srow) * Dq;
  const float* __restrict__ bx = W1 + (size_t)(n0 + srow) * Dq;

  double acc[8][8];
#pragma unroll
  for (int i = 0; i < 8; ++i)
#pragma unroll
    for (int j = 0; j < 8; ++j) acc[i][j] = 0.0;

  // prologue: stage slab 0 (k 0..11)
  {
    const float4 a4 = *(const float4*)(ax + kc6);
    const float2 a2 = *(const float2*)(ax + kc6 + 4);
    const float4 b4 = *(const float4*)(bx + kc6);
    const float2 b2 = *(const float2*)(bx + kc6 + 4);
    Xs[0][kc6 + 0][schunk] = (double)a4.x;
    Xs[0][kc6 + 1][schunk] = (double)a4.y;
    Xs[0][kc6 + 2][schunk] = (double)a4.z;
    Xs[0][kc6 + 3][schunk] = (double)a4.w;
    Xs[0][kc6 + 4][schunk] = (double)a2.x;
    Xs[0][kc6 + 5][schunk] = (double)a2.y;
    Ws[0][kc6 + 0][schunk] = (double)b4.x;
    Ws[0][kc6 + 1][schunk] = (double)b4.y;
    Ws[0][kc6 + 2][schunk] = (double)b4.z;
    Ws[0][kc6 + 3][schunk] = (double)b4.w;
    Ws[0][kc6 + 4][schunk] = (double)b2.x;
    Ws[0][kc6 + 5][schunk] = (double)b2.y;
  }
  __syncthreads();

#define FRAG_STEP(BUF, KK)                                               \
  do {                                                                   \
    double a[8], b[8];                                                   \
    *(double2*)&a[0] = *(const double2*)&Xs[BUF][KK][ty * 10 + 0];       \
    *(double2*)&a[2] = *(const double2*)&Xs[BUF][KK][ty * 10 + 2];       \
    *(double2*)&a[4] = *(const double2*)&Xs[BUF][KK][ty * 10 + 4];       \
    *(double2*)&a[6] = *(const double2*)&Xs[BUF][KK][ty * 10 + 6];       \
    *(double2*)&b[0] = *(const double2*)&Ws[BUF][KK][tx * 10 + 0];       \
    *(double2*)&b[2] = *(const double2*)&Ws[BUF][KK][tx * 10 + 2];       \
    *(double2*)&b[4] = *(const double2*)&Ws[BUF][KK][tx * 10 + 4];       \
    *(double2*)&b[6] = *(const double2*)&Ws[BUF][KK][tx * 10 + 6];       \
    _Pragma("unroll") for (int i = 0; i < 8; ++i)                        \
        _Pragma("unroll") for (int j = 0; j < 8; ++j)                    \
            acc[i][j] = fma(a[i], b[j], acc[i][j]);                      \
  } while (0)

  // 193 slabs: s=0..191 width 12 (k = s*12..), s=192 width 8 (k=2304..2311)
  for (int s = 0; s < 193; ++s) {
    const int buf = s & 1;
    float4 a4, b4;
    float2 a2, b2;
    const bool hasNext = (s + 1 < 193);
    const bool nextFull = (s + 1 < 192);
    if (hasNext) {
      const int nk = (s + 1) * 12;
      if (nextFull) {
        a4 = *(const float4*)(ax + nk + kc6);
        a2 = *(const float2*)(ax + nk + kc6 + 4);
        b4 = *(const float4*)(bx + nk + kc6);
        b2 = *(const float2*)(bx + nk + kc6 + 4);
      } else {  // tail slab, width 8
        a4 = *(const float4*)(ax + 2304 + kc4);
        b4 = *(const float4*)(bx + 2304 + kc4);
      }
    }
    if (s < 192) {
#pragma unroll
      for (int kk = 0; kk < 12; ++kk) FRAG_STEP(buf, kk);
    } else {
#pragma unroll
      for (int kk = 0; kk < 8; ++kk) FRAG_STEP(buf, kk);
    }
    if (hasNext) {
      const int nb = buf ^ 1;
      if (nextFull) {
        Xs[nb][kc6 + 0][schunk] = (double)a4.x;
        Xs[nb][kc6 + 1][schunk] = (double)a4.y;
        Xs[nb][kc6 + 2][schunk] = (double)a4.z;
        Xs[nb][kc6 + 3][schunk] = (double)a4.w;
        Xs[nb][kc6 + 4][schunk] = (double)a2.x;
        Xs[nb][kc6 + 5][schunk] = (double)a2.y;
        Ws[nb][kc6 + 0][schunk] = (double)b4.x;
        Ws[nb][kc6 + 1][schunk] = (double)b4.y;
        Ws[nb][kc6 + 2][schunk] = (double)b4.z;
        Ws[nb][kc6 + 3][schunk] = (double)b4.w;
        Ws[nb][kc6 + 4][schunk] = (double)b2.x;
        Ws[nb][kc6 + 5][schunk] = (double)b2.y;
      } else {
        Xs[nb][kc4 + 0][schunk] = (double)a4.x;
        Xs[nb][kc4 + 1][schunk] = (double)a4.y;
        Xs[nb][kc4 + 2][schunk] = (double)a4.z;
        Xs[nb][kc4 + 3][schunk] = (double)a4.w;
        Ws[nb][kc4 + 0][schunk] = (double)b4.x;
        Ws[nb][kc4 + 1][schunk] = (double)b4.y;
        Ws[nb][kc4 + 2][schunk] = (double)b4.z;
        Ws[nb][kc4 + 3][schunk] = (double)b4.w;
      }
      __syncthreads();
    }
  }
#undef FRAG_STEP

  float bl[8];
  *(float4*)&bl[0] = *(const float4*)(b1 + n0 + tx * 8);
  *(float4*)&bl[4] = *(const float4*)(b1 + n0 + tx * 8 + 4);
#pragma unroll
  for (int i = 0; i < 8; ++i) {
    float* crow = cur1 + (m0 + ty * 8 + i) * Hq + n0 + tx * 8;
    float4 v0, v1;
    v0.x = __fadd_rn((float)acc[i][0], bl[0]);
    v0.y = __fadd_rn((float)acc[i][1], bl[1]);
    v0.z = __fadd_rn((float)acc[i][2], bl[2]);
    v0.w = __fadd_rn((float)acc[i][3], bl[3]);
    v1.x = __fadd_rn((float)acc[i][4], bl[4]);
    v1.y = __fadd_rn((float)acc[i][5], bl[5]);
    v1.z = __fadd_rn((float)acc[i][6], bl[6]);
    v1.w = __fadd_rn((float)acc[i][7], bl[7]);
    *(float4*)(crow) = v0;
    *(float4*)(crow + 4) = v1;
  }
}

// ---------------- K2 helpers: pipelined sparse gather (WrT f32; cvt exact)
__device__ __forceinline__ void gather8(const unsigned short* __restrict__ row,
                                        int base, int j,
                                        const float* __restrict__ WrTf,
                                        double* g) {
  const uint4 pk = *(const uint4*)&row[base];
  const int k0 = pk.x & 0xffff, k1 = pk.x >> 16;
  const int k2 = pk.y & 0xffff, k3 = pk.y >> 16;
  const int k4 = pk.z & 0xffff, k5 = pk.z >> 16;
  const int k6 = pk.w & 0xffff, k7 = pk.w >> 16;
  g[0] = (double)WrTf[(size_t)k0 * Hq + j];
  g[1] = (double)WrTf[(size_t)k1 * Hq + j];
  g[2] = (double)WrTf[(size_t)k2 * Hq + j];
  g[3] = (double)WrTf[(size_t)k3 * Hq + j];
  g[4] = (double)WrTf[(size_t)k4 * Hq + j];
  g[5] = (double)WrTf[(size_t)k5 * Hq + j];
  g[6] = (double)WrTf[(size_t)k6 * Hq + j];
  g[7] = (double)WrTf[(size_t)k7 * Hq + j];
}
__device__ __forceinline__ void acc8(const double* g, int rem, double& rA,
                                     double& rB, double& rC, double& rD) {
  if (rem >= 8) {
    rA += g[0]; rB += g[1]; rC += g[2]; rD += g[3];
    rA += g[4]; rB += g[5]; rC += g[6]; rD += g[7];
  } else {
    if (rem > 0) rA += g[0];
    if (rem > 1) rB += g[1];
    if (rem > 2) rC += g[2];
    if (rem > 3) rD += g[3];
    if (rem > 4) rA += g[4];
    if (rem > 5) rB += g[5];
    if (rem > 6) rC += g[6];
  }
}

// ---------------- K2: sparse-spike recurrent scan (v19 verbatim)
__global__ __launch_bounds__(512) void snn_scan(
    const float* __restrict__ cur1, const float* __restrict__ WrTf,
    const float* __restrict__ br, const float* __restrict__ W2,
    const float* __restrict__ b2, float* __restrict__ out, int b_off) {
  __shared__ float spkF[4][512];
  __shared__ unsigned short idxL[4][512];
  __shared__ unsigned long long masksL[4][8];
  __shared__ int cnts[4];

  const int j = threadIdx.x;
  const int wv = j >> 6;
  const int lane = j & 63;
  const int lb = blockIdx.x * 4;
  const int gb = b_off + lb;

  float m1[4] = {0.f, 0.f, 0.f, 0.f};
  float m2 = 0.f;
#pragma unroll
  for (int r = 0; r < 4; ++r) { spkF[r][j] = 0.f; idxL[r][j] = 0; }
  if (j < 4) cnts[j] = 0;
  __syncthreads();

  const float brr = br[j];

  const int g = j >> 3, l = j & 7;
  const int r2g = g / 10, o2 = g - r2g * 10;
  const bool doB = (j < 320);
  const float b2v = doB ? b2[o2] : 0.f;
  const float* __restrict__ w2p = doB ? (W2 + (size_t)o2 * Hq) : W2;

  for (int t = 0; t < Tq; ++t) {
    float c1[4];
#pragma unroll
    for (int r = 0; r < 4; ++r)
      c1[r] = cur1[((size_t)(lb + r) * Tq + t) * Hq + j];

    double rec[4];
#pragma unroll
    for (int r = 0; r < 4; ++r) {
      const int cnt = cnts[r];
      double rA = 0.0, rB = 0.0, rC = 0.0, rD = 0.0;
      double g0[8], g1[8];
      if (cnt > 0) gather8(&idxL[r][0], 0, j, WrTf, g0);
      for (int i0 = 0; i0 < cnt; i0 += 16) {
        if (i0 + 8 < cnt) gather8(&idxL[r][0], i0 + 8, j, WrTf, g1);
        acc8(g0, cnt - i0, rA, rB, rC, rD);
        if (i0 + 16 < cnt) gather8(&idxL[r][0], i0 + 16, j, WrTf, g0);
        if (i0 + 8 < cnt) acc8(g1, cnt - (i0 + 8), rA, rB, rC, rD);
      }
      rec[r] = (rA + rB) + (rC + rD);
    }
    __syncthreads();

    unsigned long long bm[4];
    int bits = 0;
#pragma unroll
    for (int r = 0; r < 4; ++r) {
      const float rst = (m1[r] - 1.0f > 0.0f) ? 1.0f : 0.0f;
      const float mn = __fsub_rn(
          __fadd_rn(__fadd_rn(__fmul_rn(0.99f, m1[r]), c1[r]),
                    __fadd_rn((float)rec[r], brr)),
          rst);
      m1[r] = mn;
      const bool bit = (mn - 1.0f > 0.0f);
      spkF[r][j] = bit ? 1.0f : 0.0f;
      if (bit) bits |= (1 << r);
      bm[r] = __ballot(bit);
      if (lane == 0) masksL[r][wv] = bm[r];
    }
    __syncthreads();

#pragma unroll
    for (int r = 0; r < 4; ++r) {
      int base = 0;
#pragma unroll
      for (int w = 0; w < 8; ++w)
        if (w < wv) base += __popcll(masksL[r][w]);
      if (bits & (1 << r)) {
        const int pos = base + __popcll(bm[r] & ((1ull << lane) - 1ull));
        idxL[r][pos] = (unsigned short)j;
      }
    }
    if (j < 4) {
      int c = 0;
#pragma unroll
      for (int w = 0; w < 8; ++w) c += __popcll(masksL[j][w]);
      cnts[j] = c;
    }
    if (doB) {
      double p = 0.0;
#pragma unroll
      for (int s8 = 0; s8 < 64; ++s8) {
        const int k = l + (s8 << 3);
        p = fma((double)spkF[r2g][k], (double)w2p[k], p);
      }
      p += __shfl_down(p, 4, 8);
      p += __shfl_down(p, 2, 8);
      p += __shfl_down(p, 1, 8);
      if (l == 0) {
        const float cur2 = __fadd_rn((float)p, b2v);
        const float rst2 = (m2 - 1.0f > 0.0f) ? 1.0f : 0.0f;
        const float mn2 =
            __fsub_rn(__fadd_rn(__fmul_rn(0.99f, m2), cur2), rst2);
        m2 = mn2;
        const size_t oidx = ((size_t)t * Bq + (gb + r2g)) * Oq + o2;
        out[oidx] = (mn2 - 1.0f > 0.0f) ? 1.0f : 0.0f;
        out[(size_t)Tq * Bq * Oq + oidx] = mn2;
      }
    }
    __syncthreads();
  }
}

extern "C" void kernel_launch(void* const* d_in, const int* in_sizes, int n_in,
                              void* d_out, int out_size, void* d_ws, size_t ws_size,
                              hipStream_t stream) {
  const float* x  = (const float*)d_in[0];
  const float* W1 = (const float*)d_in[1];
  const float* b1 = (const float*)d_in[2];
  const float* Wr = (const float*)d_in[3];
  const float* br = (const float*)d_in[4];
  const float* W2 = (const float*)d_in[5];
  const float* b2 = (const float*)d_in[6];
  float* out = (float*)d_out;  // FP32
  (void)in_sizes; (void)n_in; (void)out_size;

  float* WrTf = (float*)d_ws;                        // 1 MB
  float* cur1 = (float*)d_ws + Hq * Hq;              // after WrTf
  const size_t avail = ws_size - (size_t)Hq * Hq * sizeof(float);

  snn_wrt<<<dim3(16, 16), 256, 0, stream>>>(Wr, WrTf);

  int nb = Bq;
  while (nb > 4 && (size_t)nb * Tq * Hq * sizeof(float) > avail) nb >>= 1;

  for (int b_off = 0; b_off < Bq; b_off += nb) {
    snn_fc1_gemm<<<dim3(Hq / 128, nb * Tq / 128), 256, 0, stream>>>(
        x + (size_t)b_off * Tq * Dq, W1, b1, cur1);
    snn_scan<<<nb / 4, 512, 0, stream>>>(cur1, WrTf, br, W2, b2, out, b_off);
  }
}

// Round 21
// 2285.963 us; speedup vs baseline: 1.5656x; 1.0364x over previous
//
#include <hip/hip_runtime.h>

// Net_46076409152296: spiking net fwd (RLeaky+Leaky). B=1024,T=32,D=2312,H=512,O=10.
// v21: K1 stores BOTH tiles f32 in LDS (halves LDS-pipe traffic, the measured
// bottleneck) with stride-12 chunk padding so all float4 reads stay 16B-aligned
// (v18's regression was misaligned ty*10 f32 reads -> split loads, not cvt cost).
// f32->f64 cvt in registers is exact; fma order unchanged -> bit-identical.
// BK=12 (+8 tail) kept from v20. K0 + sparse-f32-WrT K2 + launcher verbatim.

constexpr int Bq = 1024, Tq = 32, Dq = 2312, Hq = 512, Oq = 10;

// ---------------- K0: WrTf[k][j] = Wr[j][k]  (f32 coalesced transpose)
__global__ __launch_bounds__(256) void snn_wrt(
    const float* __restrict__ Wr, float* __restrict__ WrTf) {
  __shared__ float t[32][33];
  const int bx = blockIdx.x;
  const int by = blockIdx.y;
  const int lx = threadIdx.x & 31, ly = threadIdx.x >> 5;
#pragma unroll
  for (int i = 0; i < 4; ++i)
    t[ly + 8 * i][lx] = Wr[(size_t)(by * 32 + ly + 8 * i) * Hq + bx * 32 + lx];
  __syncthreads();
#pragma unroll
  for (int i = 0; i < 4; ++i)
    WrTf[(size_t)(bx * 32 + ly + 8 * i) * Hq + by * 32 + lx] = t[lx][ly + 8 * i];
}

// ---------------- K1: C[m][n] = f64dot(x[m,:], W1[n,:]) + b1[n]
// 128x128 tile, 256 thr, 8x8 f64 micro, BK=12 (+8 tail).
// LDS f32, chunk c at [kk][c*12 .. c*12+7] (48B stride: float4-aligned).
__global__ __launch_bounds__(256) void snn_fc1_gemm(
    const float* __restrict__ x, const float* __restrict__ W1,
    const float* __restrict__ b1, float* __restrict__ cur1) {
  __shared__ float Xs[2][12][192];   // 18.4 KB
  __shared__ float Ws[2][12][192];   // 18.4 KB

  const int tid = threadIdx.x;
  const int tx = tid & 15;
  const int ty = tid >> 4;
  const size_t m0 = (size_t)blockIdx.y * 128;
  const int n0 = blockIdx.x * 128;
  const int srow = tid >> 1;              // 0..127
  const int kc6 = (tid & 1) * 6;          // main slabs (width 12)
  const int kc4 = (tid & 1) * 4;          // tail slab (width 8)
  const int schunk = (srow >> 3) * 12 + (srow & 7);
  const float* __restrict__ ax = x + (m0 + srow) * Dq;
  const float* __restrict__ bx = W1 + (size_t)(n0 + srow) * Dq;

  double acc[8][8];
#pragma unroll
  for (int i = 0; i < 8; ++i)
#pragma unroll
    for (int j = 0; j < 8; ++j) acc[i][j] = 0.0;

  // prologue: stage slab 0 (k 0..11), f32 direct
  {
    const float4 a4 = *(const float4*)(ax + kc6);
    const float2 a2 = *(const float2*)(ax + kc6 + 4);
    const float4 b4 = *(const float4*)(bx + kc6);
    const float2 b2 = *(const float2*)(bx + kc6 + 4);
    Xs[0][kc6 + 0][schunk] = a4.x;
    Xs[0][kc6 + 1][schunk] = a4.y;
    Xs[0][kc6 + 2][schunk] = a4.z;
    Xs[0][kc6 + 3][schunk] = a4.w;
    Xs[0][kc6 + 4][schunk] = a2.x;
    Xs[0][kc6 + 5][schunk] = a2.y;
    Ws[0][kc6 + 0][schunk] = b4.x;
    Ws[0][kc6 + 1][schunk] = b4.y;
    Ws[0][kc6 + 2][schunk] = b4.z;
    Ws[0][kc6 + 3][schunk] = b4.w;
    Ws[0][kc6 + 4][schunk] = b2.x;
    Ws[0][kc6 + 5][schunk] = b2.y;
  }
  __syncthreads();

#define FRAG_STEP(BUF, KK)                                               \
  do {                                                                   \
    float af[8], bf[8];                                                  \
    *(float4*)&af[0] = *(const float4*)&Xs[BUF][KK][ty * 12 + 0];        \
    *(float4*)&af[4] = *(const float4*)&Xs[BUF][KK][ty * 12 + 4];        \
    *(float4*)&bf[0] = *(const float4*)&Ws[BUF][KK][tx * 12 + 0];        \
    *(float4*)&bf[4] = *(const float4*)&Ws[BUF][KK][tx * 12 + 4];        \
    double ad[8], bd[8];                                                 \
    _Pragma("unroll") for (int i = 0; i < 8; ++i) {                      \
      ad[i] = (double)af[i];                                             \
      bd[i] = (double)bf[i];                                             \
    }                                                                    \
    _Pragma("unroll") for (int i = 0; i < 8; ++i)                        \
        _Pragma("unroll") for (int j = 0; j < 8; ++j)                    \
            acc[i][j] = fma(ad[i], bd[j], acc[i][j]);                    \
  } while (0)

  // 193 slabs: s=0..191 width 12, s=192 width 8 (k = 2304..2311)
  for (int s = 0; s < 193; ++s) {
    const int buf = s & 1;
    float4 a4, b4;
    float2 a2, b2;
    const bool hasNext = (s + 1 < 193);
    const bool nextFull = (s + 1 < 192);
    if (hasNext) {
      const int nk = (s + 1) * 12;
      if (nextFull) {
        a4 = *(const float4*)(ax + nk + kc6);
        a2 = *(const float2*)(ax + nk + kc6 + 4);
        b4 = *(const float4*)(bx + nk + kc6);
        b2 = *(const float2*)(bx + nk + kc6 + 4);
      } else {
        a4 = *(const float4*)(ax + 2304 + kc4);
        b4 = *(const float4*)(bx + 2304 + kc4);
      }
    }
    if (s < 192) {
#pragma unroll
      for (int kk = 0; kk < 12; ++kk) FRAG_STEP(buf, kk);
    } else {
#pragma unroll
      for (int kk = 0; kk < 8; ++kk) FRAG_STEP(buf, kk);
    }
    if (hasNext) {
      const int nb = buf ^ 1;
      if (nextFull) {
        Xs[nb][kc6 + 0][schunk] = a4.x;
        Xs[nb][kc6 + 1][schunk] = a4.y;
        Xs[nb][kc6 + 2][schunk] = a4.z;
        Xs[nb][kc6 + 3][schunk] = a4.w;
        Xs[nb][kc6 + 4][schunk] = a2.x;
        Xs[nb][kc6 + 5][schunk] = a2.y;
        Ws[nb][kc6 + 0][schunk] = b4.x;
        Ws[nb][kc6 + 1][schunk] = b4.y;
        Ws[nb][kc6 + 2][schunk] = b4.z;
        Ws[nb][kc6 + 3][schunk] = b4.w;
        Ws[nb][kc6 + 4][schunk] = b2.x;
        Ws[nb][kc6 + 5][schunk] = b2.y;
      } else {
        Xs[nb][kc4 + 0][schunk] = a4.x;
        Xs[nb][kc4 + 1][schunk] = a4.y;
        Xs[nb][kc4 + 2][schunk] = a4.z;
        Xs[nb][kc4 + 3][schunk] = a4.w;
        Ws[nb][kc4 + 0][schunk] = b4.x;
        Ws[nb][kc4 + 1][schunk] = b4.y;
        Ws[nb][kc4 + 2][schunk] = b4.z;
        Ws[nb][kc4 + 3][schunk] = b4.w;
      }
      __syncthreads();
    }
  }
#undef FRAG_STEP

  float bl[8];
  *(float4*)&bl[0] = *(const float4*)(b1 + n0 + tx * 8);
  *(float4*)&bl[4] = *(const float4*)(b1 + n0 + tx * 8 + 4);
#pragma unroll
  for (int i = 0; i < 8; ++i) {
    float* crow = cur1 + (m0 + ty * 8 + i) * Hq + n0 + tx * 8;
    float4 v0, v1;
    v0.x = __fadd_rn((float)acc[i][0], bl[0]);
    v0.y = __fadd_rn((float)acc[i][1], bl[1]);
    v0.z = __fadd_rn((float)acc[i][2], bl[2]);
    v0.w = __fadd_rn((float)acc[i][3], bl[3]);
    v1.x = __fadd_rn((float)acc[i][4], bl[4]);
    v1.y = __fadd_rn((float)acc[i][5], bl[5]);
    v1.z = __fadd_rn((float)acc[i][6], bl[6]);
    v1.w = __fadd_rn((float)acc[i][7], bl[7]);
    *(float4*)(crow) = v0;
    *(float4*)(crow + 4) = v1;
  }
}

// ---------------- K2 helpers: pipelined sparse gather (WrT f32; cvt exact)
__device__ __forceinline__ void gather8(const unsigned short* __restrict__ row,
                                        int base, int j,
                                        const float* __restrict__ WrTf,
                                        double* g) {
  const uint4 pk = *(const uint4*)&row[base];
  const int k0 = pk.x & 0xffff, k1 = pk.x >> 16;
  const int k2 = pk.y & 0xffff, k3 = pk.y >> 16;
  const int k4 = pk.z & 0xffff, k5 = pk.z >> 16;
  const int k6 = pk.w & 0xffff, k7 = pk.w >> 16;
  g[0] = (double)WrTf[(size_t)k0 * Hq + j];
  g[1] = (double)WrTf[(size_t)k1 * Hq + j];
  g[2] = (double)WrTf[(size_t)k2 * Hq + j];
  g[3] = (double)WrTf[(size_t)k3 * Hq + j];
  g[4] = (double)WrTf[(size_t)k4 * Hq + j];
  g[5] = (double)WrTf[(size_t)k5 * Hq + j];
  g[6] = (double)WrTf[(size_t)k6 * Hq + j];
  g[7] = (double)WrTf[(size_t)k7 * Hq + j];
}
__device__ __forceinline__ void acc8(const double* g, int rem, double& rA,
                                     double& rB, double& rC, double& rD) {
  if (rem >= 8) {
    rA += g[0]; rB += g[1]; rC += g[2]; rD += g[3];
    rA += g[4]; rB += g[5]; rC += g[6]; rD += g[7];
  } else {
    if (rem > 0) rA += g[0];
    if (rem > 1) rB += g[1];
    if (rem > 2) rC += g[2];
    if (rem > 3) rD += g[3];
    if (rem > 4) rA += g[4];
    if (rem > 5) rB += g[5];
    if (rem > 6) rC += g[6];
  }
}

// ---------------- K2: sparse-spike recurrent scan (v19 verbatim)
__global__ __launch_bounds__(512) void snn_scan(
    const float* __restrict__ cur1, const float* __restrict__ WrTf,
    const float* __restrict__ br, const float* __restrict__ W2,
    const float* __restrict__ b2, float* __restrict__ out, int b_off) {
  __shared__ float spkF[4][512];
  __shared__ unsigned short idxL[4][512];
  __shared__ unsigned long long masksL[4][8];
  __shared__ int cnts[4];

  const int j = threadIdx.x;
  const int wv = j >> 6;
  const int lane = j & 63;
  const int lb = blockIdx.x * 4;
  const int gb = b_off + lb;

  float m1[4] = {0.f, 0.f, 0.f, 0.f};
  float m2 = 0.f;
#pragma unroll
  for (int r = 0; r < 4; ++r) { spkF[r][j] = 0.f; idxL[r][j] = 0; }
  if (j < 4) cnts[j] = 0;
  __syncthreads();

  const float brr = br[j];

  const int g = j >> 3, l = j & 7;
  const int r2g = g / 10, o2 = g - r2g * 10;
  const bool doB = (j < 320);
  const float b2v = doB ? b2[o2] : 0.f;
  const float* __restrict__ w2p = doB ? (W2 + (size_t)o2 * Hq) : W2;

  for (int t = 0; t < Tq; ++t) {
    float c1[4];
#pragma unroll
    for (int r = 0; r < 4; ++r)
      c1[r] = cur1[((size_t)(lb + r) * Tq + t) * Hq + j];

    double rec[4];
#pragma unroll
    for (int r = 0; r < 4; ++r) {
      const int cnt = cnts[r];
      double rA = 0.0, rB = 0.0, rC = 0.0, rD = 0.0;
      double g0[8], g1[8];
      if (cnt > 0) gather8(&idxL[r][0], 0, j, WrTf, g0);
      for (int i0 = 0; i0 < cnt; i0 += 16) {
        if (i0 + 8 < cnt) gather8(&idxL[r][0], i0 + 8, j, WrTf, g1);
        acc8(g0, cnt - i0, rA, rB, rC, rD);
        if (i0 + 16 < cnt) gather8(&idxL[r][0], i0 + 16, j, WrTf, g0);
        if (i0 + 8 < cnt) acc8(g1, cnt - (i0 + 8), rA, rB, rC, rD);
      }
      rec[r] = (rA + rB) + (rC + rD);
    }
    __syncthreads();

    unsigned long long bm[4];
    int bits = 0;
#pragma unroll
    for (int r = 0; r < 4; ++r) {
      const float rst = (m1[r] - 1.0f > 0.0f) ? 1.0f : 0.0f;
      const float mn = __fsub_rn(
          __fadd_rn(__fadd_rn(__fmul_rn(0.99f, m1[r]), c1[r]),
                    __fadd_rn((float)rec[r], brr)),
          rst);
      m1[r] = mn;
      const bool bit = (mn - 1.0f > 0.0f);
      spkF[r][j] = bit ? 1.0f : 0.0f;
      if (bit) bits |= (1 << r);
      bm[r] = __ballot(bit);
      if (lane == 0) masksL[r][wv] = bm[r];
    }
    __syncthreads();

#pragma unroll
    for (int r = 0; r < 4; ++r) {
      int base = 0;
#pragma unroll
      for (int w = 0; w < 8; ++w)
        if (w < wv) base += __popcll(masksL[r][w]);
      if (bits & (1 << r)) {
        const int pos = base + __popcll(bm[r] & ((1ull << lane) - 1ull));
        idxL[r][pos] = (unsigned short)j;
      }
    }
    if (j < 4) {
      int c = 0;
#pragma unroll
      for (int w = 0; w < 8; ++w) c += __popcll(masksL[j][w]);
      cnts[j] = c;
    }
    if (doB) {
      double p = 0.0;
#pragma unroll
      for (int s8 = 0; s8 < 64; ++s8) {
        const int k = l + (s8 << 3);
        p = fma((double)spkF[r2g][k], (double)w2p[k], p);
      }
      p += __shfl_down(p, 4, 8);
      p += __shfl_down(p, 2, 8);
      p += __shfl_down(p, 1, 8);
      if (l == 0) {
        const float cur2 = __fadd_rn((float)p, b2v);
        const float rst2 = (m2 - 1.0f > 0.0f) ? 1.0f : 0.0f;
        const float mn2 =
            __fsub_rn(__fadd_rn(__fmul_rn(0.99f, m2), cur2), rst2);
        m2 = mn2;
        const size_t oidx = ((size_t)t * Bq + (gb + r2g)) * Oq + o2;
        out[oidx] = (mn2 - 1.0f > 0.0f) ? 1.0f : 0.0f;
        out[(size_t)Tq * Bq * Oq + oidx] = mn2;
      }
    }
    __syncthreads();
  }
}

extern "C" void kernel_launch(void* const* d_in, const int* in_sizes, int n_in,
                              void* d_out, int out_size, void* d_ws, size_t ws_size,
                              hipStream_t stream) {
  const float* x  = (const float*)d_in[0];
  const float* W1 = (const float*)d_in[1];
  const float* b1 = (const float*)d_in[2];
  const float* Wr = (const float*)d_in[3];
  const float* br = (const float*)d_in[4];
  const float* W2 = (const float*)d_in[5];
  const float* b2 = (const float*)d_in[6];
  float* out = (float*)d_out;  // FP32
  (void)in_sizes; (void)n_in; (void)out_size;

  float* WrTf = (float*)d_ws;                        // 1 MB
  float* cur1 = (float*)d_ws + Hq * Hq;              // after WrTf
  const size_t avail = ws_size - (size_t)Hq * Hq * sizeof(float);

  snn_wrt<<<dim3(16, 16), 256, 0, stream>>>(Wr, WrTf);

  int nb = Bq;
  while (nb > 4 && (size_t)nb * Tq * Hq * sizeof(float) > avail) nb >>= 1;

  for (int b_off = 0; b_off < Bq; b_off += nb) {
    snn_fc1_gemm<<<dim3(Hq / 128, nb * Tq / 128), 256, 0, stream>>>(
        x + (size_t)b_off * Tq * Dq, W1, b1, cur1);
    snn_scan<<<nb / 4, 512, 0, stream>>>(cur1, WrTf, br, W2, b2, out, b_off);
  }
}

// Round 22
// 2239.767 us; speedup vs baseline: 1.5979x; 1.0206x over previous
//
#include <hip/hip_runtime.h>

// Net_46076409152296: spiking net fwd (RLeaky+Leaky). B=1024,T=32,D=2312,H=512,O=10.
// v22: K1 mixed LDS tiles — Xs f64 (cvt hoisted to staging, stride-10 pad),
// Ws f32 (v21 layout). In-loop cvt 192->96 per slab/wave; a-frags load direct
// as double2 (-8 transient VGPR, guarding the 128-VGPR / 2-waves-per-SIMD
// boundary that v21's counters proved is the occupancy cliff).
// Math bit-identical (exact cvt, unchanged fma order). K0/K2/launcher verbatim.

constexpr int Bq = 1024, Tq = 32, Dq = 2312, Hq = 512, Oq = 10;

// ---------------- K0: WrTf[k][j] = Wr[j][k]  (f32 coalesced transpose)
__global__ __launch_bounds__(256) void snn_wrt(
    const float* __restrict__ Wr, float* __restrict__ WrTf) {
  __shared__ float t[32][33];
  const int bx = blockIdx.x;
  const int by = blockIdx.y;
  const int lx = threadIdx.x & 31, ly = threadIdx.x >> 5;
#pragma unroll
  for (int i = 0; i < 4; ++i)
    t[ly + 8 * i][lx] = Wr[(size_t)(by * 32 + ly + 8 * i) * Hq + bx * 32 + lx];
  __syncthreads();
#pragma unroll
  for (int i = 0; i < 4; ++i)
    WrTf[(size_t)(bx * 32 + ly + 8 * i) * Hq + by * 32 + lx] = t[lx][ly + 8 * i];
}

// ---------------- K1: C[m][n] = f64dot(x[m,:], W1[n,:]) + b1[n]
// 128x128 tile, 256 thr, 8x8 f64 micro, BK=12 (+8 tail).
// Xs f64: chunk c at [kk][c*10 .. c*10+7]; Ws f32: chunk c at [kk][c*12 .. +7].
__global__ __launch_bounds__(256) void snn_fc1_gemm(
    const float* __restrict__ x, const float* __restrict__ W1,
    const float* __restrict__ b1, float* __restrict__ cur1) {
  __shared__ double Xs[2][12][160];  // 30.7 KB
  __shared__ float  Ws[2][12][192];  // 18.4 KB

  const int tid = threadIdx.x;
  const int tx = tid & 15;
  const int ty = tid >> 4;
  const size_t m0 = (size_t)blockIdx.y * 128;
  const int n0 = blockIdx.x * 128;
  const int srow = tid >> 1;              // 0..127
  const int kc6 = (tid & 1) * 6;          // main slabs (width 12)
  const int kc4 = (tid & 1) * 4;          // tail slab (width 8)
  const int schX = (srow >> 3) * 10 + (srow & 7);   // f64 tile position
  const int schW = (srow >> 3) * 12 + (srow & 7);   // f32 tile position
  const float* __restrict__ ax = x + (m0 + srow) * Dq;
  const float* __restrict__ bx = W1 + (size_t)(n0 + srow) * Dq;

  double acc[8][8];
#pragma unroll
  for (int i = 0; i < 8; ++i)
#pragma unroll
    for (int j = 0; j < 8; ++j) acc[i][j] = 0.0;

  // prologue: stage slab 0 (k 0..11)
  {
    const float4 a4 = *(const float4*)(ax + kc6);
    const float2 a2 = *(const float2*)(ax + kc6 + 4);
    const float4 b4 = *(const float4*)(bx + kc6);
    const float2 b2 = *(const float2*)(bx + kc6 + 4);
    Xs[0][kc6 + 0][schX] = (double)a4.x;
    Xs[0][kc6 + 1][schX] = (double)a4.y;
    Xs[0][kc6 + 2][schX] = (double)a4.z;
    Xs[0][kc6 + 3][schX] = (double)a4.w;
    Xs[0][kc6 + 4][schX] = (double)a2.x;
    Xs[0][kc6 + 5][schX] = (double)a2.y;
    Ws[0][kc6 + 0][schW] = b4.x;
    Ws[0][kc6 + 1][schW] = b4.y;
    Ws[0][kc6 + 2][schW] = b4.z;
    Ws[0][kc6 + 3][schW] = b4.w;
    Ws[0][kc6 + 4][schW] = b2.x;
    Ws[0][kc6 + 5][schW] = b2.y;
  }
  __syncthreads();

#define FRAG_STEP(BUF, KK)                                               \
  do {                                                                   \
    double a[8];                                                         \
    *(double2*)&a[0] = *(const double2*)&Xs[BUF][KK][ty * 10 + 0];       \
    *(double2*)&a[2] = *(const double2*)&Xs[BUF][KK][ty * 10 + 2];       \
    *(double2*)&a[4] = *(const double2*)&Xs[BUF][KK][ty * 10 + 4];       \
    *(double2*)&a[6] = *(const double2*)&Xs[BUF][KK][ty * 10 + 6];       \
    float bf[8];                                                         \
    *(float4*)&bf[0] = *(const float4*)&Ws[BUF][KK][tx * 12 + 0];        \
    *(float4*)&bf[4] = *(const float4*)&Ws[BUF][KK][tx * 12 + 4];        \
    double bd[8];                                                        \
    _Pragma("unroll") for (int i = 0; i < 8; ++i) bd[i] = (double)bf[i]; \
    _Pragma("unroll") for (int i = 0; i < 8; ++i)                        \
        _Pragma("unroll") for (int j = 0; j < 8; ++j)                    \
            acc[i][j] = fma(a[i], bd[j], acc[i][j]);                     \
  } while (0)

  // 193 slabs: s=0..191 width 12, s=192 width 8 (k = 2304..2311)
  for (int s = 0; s < 193; ++s) {
    const int buf = s & 1;
    float4 a4, b4;
    float2 a2, b2;
    const bool hasNext = (s + 1 < 193);
    const bool nextFull = (s + 1 < 192);
    if (hasNext) {
      const int nk = (s + 1) * 12;
      if (nextFull) {
        a4 = *(const float4*)(ax + nk + kc6);
        a2 = *(const float2*)(ax + nk + kc6 + 4);
        b4 = *(const float4*)(bx + nk + kc6);
        b2 = *(const float2*)(bx + nk + kc6 + 4);
      } else {
        a4 = *(const float4*)(ax + 2304 + kc4);
        b4 = *(const float4*)(bx + 2304 + kc4);
      }
    }
    if (s < 192) {
#pragma unroll
      for (int kk = 0; kk < 12; ++kk) FRAG_STEP(buf, kk);
    } else {
#pragma unroll
      for (int kk = 0; kk < 8; ++kk) FRAG_STEP(buf, kk);
    }
    if (hasNext) {
      const int nb = buf ^ 1;
      if (nextFull) {
        Xs[nb][kc6 + 0][schX] = (double)a4.x;
        Xs[nb][kc6 + 1][schX] = (double)a4.y;
        Xs[nb][kc6 + 2][schX] = (double)a4.z;
        Xs[nb][kc6 + 3][schX] = (double)a4.w;
        Xs[nb][kc6 + 4][schX] = (double)a2.x;
        Xs[nb][kc6 + 5][schX] = (double)a2.y;
        Ws[nb][kc6 + 0][schW] = b4.x;
        Ws[nb][kc6 + 1][schW] = b4.y;
        Ws[nb][kc6 + 2][schW] = b4.z;
        Ws[nb][kc6 + 3][schW] = b4.w;
        Ws[nb][kc6 + 4][schW] = b2.x;
        Ws[nb][kc6 + 5][schW] = b2.y;
      } else {
        Xs[nb][kc4 + 0][schX] = (double)a4.x;
        Xs[nb][kc4 + 1][schX] = (double)a4.y;
        Xs[nb][kc4 + 2][schX] = (double)a4.z;
        Xs[nb][kc4 + 3][schX] = (double)a4.w;
        Ws[nb][kc4 + 0][schW] = b4.x;
        Ws[nb][kc4 + 1][schW] = b4.y;
        Ws[nb][kc4 + 2][schW] = b4.z;
        Ws[nb][kc4 + 3][schW] = b4.w;
      }
      __syncthreads();
    }
  }
#undef FRAG_STEP

  float bl[8];
  *(float4*)&bl[0] = *(const float4*)(b1 + n0 + tx * 8);
  *(float4*)&bl[4] = *(const float4*)(b1 + n0 + tx * 8 + 4);
#pragma unroll
  for (int i = 0; i < 8; ++i) {
    float* crow = cur1 + (m0 + ty * 8 + i) * Hq + n0 + tx * 8;
    float4 v0, v1;
    v0.x = __fadd_rn((float)acc[i][0], bl[0]);
    v0.y = __fadd_rn((float)acc[i][1], bl[1]);
    v0.z = __fadd_rn((float)acc[i][2], bl[2]);
    v0.w = __fadd_rn((float)acc[i][3], bl[3]);
    v1.x = __fadd_rn((float)acc[i][4], bl[4]);
    v1.y = __fadd_rn((float)acc[i][5], bl[5]);
    v1.z = __fadd_rn((float)acc[i][6], bl[6]);
    v1.w = __fadd_rn((float)acc[i][7], bl[7]);
    *(float4*)(crow) = v0;
    *(float4*)(crow + 4) = v1;
  }
}

// ---------------- K2 helpers: pipelined sparse gather (WrT f32; cvt exact)
__device__ __forceinline__ void gather8(const unsigned short* __restrict__ row,
                                        int base, int j,
                                        const float* __restrict__ WrTf,
                                        double* g) {
  const uint4 pk = *(const uint4*)&row[base];
  const int k0 = pk.x & 0xffff, k1 = pk.x >> 16;
  const int k2 = pk.y & 0xffff, k3 = pk.y >> 16;
  const int k4 = pk.z & 0xffff, k5 = pk.z >> 16;
  const int k6 = pk.w & 0xffff, k7 = pk.w >> 16;
  g[0] = (double)WrTf[(size_t)k0 * Hq + j];
  g[1] = (double)WrTf[(size_t)k1 * Hq + j];
  g[2] = (double)WrTf[(size_t)k2 * Hq + j];
  g[3] = (double)WrTf[(size_t)k3 * Hq + j];
  g[4] = (double)WrTf[(size_t)k4 * Hq + j];
  g[5] = (double)WrTf[(size_t)k5 * Hq + j];
  g[6] = (double)WrTf[(size_t)k6 * Hq + j];
  g[7] = (double)WrTf[(size_t)k7 * Hq + j];
}
__device__ __forceinline__ void acc8(const double* g, int rem, double& rA,
                                     double& rB, double& rC, double& rD) {
  if (rem >= 8) {
    rA += g[0]; rB += g[1]; rC += g[2]; rD += g[3];
    rA += g[4]; rB += g[5]; rC += g[6]; rD += g[7];
  } else {
    if (rem > 0) rA += g[0];
    if (rem > 1) rB += g[1];
    if (rem > 2) rC += g[2];
    if (rem > 3) rD += g[3];
    if (rem > 4) rA += g[4];
    if (rem > 5) rB += g[5];
    if (rem > 6) rC += g[6];
  }
}

// ---------------- K2: sparse-spike recurrent scan (v19 verbatim)
__global__ __launch_bounds__(512) void snn_scan(
    const float* __restrict__ cur1, const float* __restrict__ WrTf,
    const float* __restrict__ br, const float* __restrict__ W2,
    const float* __restrict__ b2, float* __restrict__ out, int b_off) {
  __shared__ float spkF[4][512];
  __shared__ unsigned short idxL[4][512];
  __shared__ unsigned long long masksL[4][8];
  __shared__ int cnts[4];

  const int j = threadIdx.x;
  const int wv = j >> 6;
  const int lane = j & 63;
  const int lb = blockIdx.x * 4;
  const int gb = b_off + lb;

  float m1[4] = {0.f, 0.f, 0.f, 0.f};
  float m2 = 0.f;
#pragma unroll
  for (int r = 0; r < 4; ++r) { spkF[r][j] = 0.f; idxL[r][j] = 0; }
  if (j < 4) cnts[j] = 0;
  __syncthreads();

  const float brr = br[j];

  const int g = j >> 3, l = j & 7;
  const int r2g = g / 10, o2 = g - r2g * 10;
  const bool doB = (j < 320);
  const float b2v = doB ? b2[o2] : 0.f;
  const float* __restrict__ w2p = doB ? (W2 + (size_t)o2 * Hq) : W2;

  for (int t = 0; t < Tq; ++t) {
    float c1[4];
#pragma unroll
    for (int r = 0; r < 4; ++r)
      c1[r] = cur1[((size_t)(lb + r) * Tq + t) * Hq + j];

    double rec[4];
#pragma unroll
    for (int r = 0; r < 4; ++r) {
      const int cnt = cnts[r];
      double rA = 0.0, rB = 0.0, rC = 0.0, rD = 0.0;
      double g0[8], g1[8];
      if (cnt > 0) gather8(&idxL[r][0], 0, j, WrTf, g0);
      for (int i0 = 0; i0 < cnt; i0 += 16) {
        if (i0 + 8 < cnt) gather8(&idxL[r][0], i0 + 8, j, WrTf, g1);
        acc8(g0, cnt - i0, rA, rB, rC, rD);
        if (i0 + 16 < cnt) gather8(&idxL[r][0], i0 + 16, j, WrTf, g0);
        if (i0 + 8 < cnt) acc8(g1, cnt - (i0 + 8), rA, rB, rC, rD);
      }
      rec[r] = (rA + rB) + (rC + rD);
    }
    __syncthreads();

    unsigned long long bm[4];
    int bits = 0;
#pragma unroll
    for (int r = 0; r < 4; ++r) {
      const float rst = (m1[r] - 1.0f > 0.0f) ? 1.0f : 0.0f;
      const float mn = __fsub_rn(
          __fadd_rn(__fadd_rn(__fmul_rn(0.99f, m1[r]), c1[r]),
                    __fadd_rn((float)rec[r], brr)),
          rst);
      m1[r] = mn;
      const bool bit = (mn - 1.0f > 0.0f);
      spkF[r][j] = bit ? 1.0f : 0.0f;
      if (bit) bits |= (1 << r);
      bm[r] = __ballot(bit);
      if (lane == 0) masksL[r][wv] = bm[r];
    }
    __syncthreads();

#pragma unroll
    for (int r = 0; r < 4; ++r) {
      int base = 0;
#pragma unroll
      for (int w = 0; w < 8; ++w)
        if (w < wv) base += __popcll(masksL[r][w]);
      if (bits & (1 << r)) {
        const int pos = base + __popcll(bm[r] & ((1ull << lane) - 1ull));
        idxL[r][pos] = (unsigned short)j;
      }
    }
    if (j < 4) {
      int c = 0;
#pragma unroll
      for (int w = 0; w < 8; ++w) c += __popcll(masksL[j][w]);
      cnts[j] = c;
    }
    if (doB) {
      double p = 0.0;
#pragma unroll
      for (int s8 = 0; s8 < 64; ++s8) {
        const int k = l + (s8 << 3);
        p = fma((double)spkF[r2g][k], (double)w2p[k], p);
      }
      p += __shfl_down(p, 4, 8);
      p += __shfl_down(p, 2, 8);
      p += __shfl_down(p, 1, 8);
      if (l == 0) {
        const float cur2 = __fadd_rn((float)p, b2v);
        const float rst2 = (m2 - 1.0f > 0.0f) ? 1.0f : 0.0f;
        const float mn2 =
            __fsub_rn(__fadd_rn(__fmul_rn(0.99f, m2), cur2), rst2);
        m2 = mn2;
        const size_t oidx = ((size_t)t * Bq + (gb + r2g)) * Oq + o2;
        out[oidx] = (mn2 - 1.0f > 0.0f) ? 1.0f : 0.0f;
        out[(size_t)Tq * Bq * Oq + oidx] = mn2;
      }
    }
    __syncthreads();
  }
}

extern "C" void kernel_launch(void* const* d_in, const int* in_sizes, int n_in,
                              void* d_out, int out_size, void* d_ws, size_t ws_size,
                              hipStream_t stream) {
  const float* x  = (const float*)d_in[0];
  const float* W1 = (const float*)d_in[1];
  const float* b1 = (const float*)d_in[2];
  const float* Wr = (const float*)d_in[3];
  const float* br = (const float*)d_in[4];
  const float* W2 = (const float*)d_in[5];
  const float* b2 = (const float*)d_in[6];
  float* out = (float*)d_out;  // FP32
  (void)in_sizes; (void)n_in; (void)out_size;

  float* WrTf = (float*)d_ws;                        // 1 MB
  float* cur1 = (float*)d_ws + Hq * Hq;              // after WrTf
  const size_t avail = ws_size - (size_t)Hq * Hq * sizeof(float);

  snn_wrt<<<dim3(16, 16), 256, 0, stream>>>(Wr, WrTf);

  int nb = Bq;
  while (nb > 4 && (size_t)nb * Tq * Hq * sizeof(float) > avail) nb >>= 1;

  for (int b_off = 0; b_off < Bq; b_off += nb) {
    snn_fc1_gemm<<<dim3(Hq / 128, nb * Tq / 128), 256, 0, stream>>>(
        x + (size_t)b_off * Tq * Dq, W1, b1, cur1);
    snn_scan<<<nb / 4, 512, 0, stream>>>(cur1, WrTf, br, W2, b2, out, b_off);
  }
}